// Round 16
// baseline (16.886 us; speedup 1.0000x reference)
//
#include <hip/hip_runtime.h>
#include <stdint.h>

// NeRF "mark untrained cells": out[cas][m] = visible(cas, morton_decode(m)) ? density[cas][m] : -1
//
// Structure = round 12/14 (VALIDATED 15.7us, absmax 0.0): 8 cells/thread (2x2x2 per lane),
// wave = 8x8x8 box, 4096 waves, 1024 blocks x 256 threads, 5-plane SAT cull + exact
// silhouette tests.
//
// Round-15 lesson (16.66us, REGRESSED): dg loads hoisted BEFORE __syncthreads get drained
// at the barrier (syncthreads = s_waitcnt vmcnt(0) + s_barrier) -> serialized HBM latency
// before classify. THIS ROUND: same hoist but AFTER the barrier -- no barrier between
// issue and use; latency hides under decode+classify+ballots+phase-2; compiler waits
// vmcnt at first epilogue use. (r12/r14 had the loads after phase-2 in source; compiler
// does not hoist global loads across a data-dependent while loop.)

constexpr int GRIDN  = 128;
constexpr int NCELLS = GRIDN * GRIDN * GRIDN;   // 2097152
constexpr int NCAMS  = 32;
constexpr int BLOCK  = 256;
constexpr int CPB    = BLOCK * 8;               // 2048 cells per block

__device__ __forceinline__ uint32_t compact1by2(uint32_t x) {
    // inverse of reference _part1by2 (valid for 21-bit morton codes)
    x &= 0x09249249u;
    x = (x ^ (x >> 2))  & 0x030c30c3u;
    x = (x ^ (x >> 4))  & 0x0300f00fu;
    x = (x ^ (x >> 8))  & 0x030000ffu;
    x = (x ^ (x >> 16)) & 0x000003ffu;
    return x;
}

__launch_bounds__(BLOCK)
__global__ void nerf_mark_kernel(const float* __restrict__ dg,
                                 const float* __restrict__ poses,
                                 const float* __restrict__ intr,
                                 float* __restrict__ out) {
    // one 48B record per camera: R0..R8, dx, dy, dz  (16B aligned -> 3x ds_read_b128)
    __shared__ __align__(16) float sRd[NCAMS * 12];
    __shared__ float sc0[GRIDN];      // c0 table: round((2i/127 - 1) * S0)
    __shared__ float sax[2];          // cx/fx, cy/fy

    constexpr float S0  = 1.0f - 1.0f / 128.0f;   // 127/128, exact
    constexpr float T0  = 2.0f / 128.0f, T1 = 4.0f / 128.0f, T2 = 8.0f / 128.0f;
    constexpr float PAD = 1e-3f;                  // >> worst-case fp error (~4e-5)

    const int tid = threadIdx.x;
    for (int i = tid; i < NCAMS * 12; i += BLOCK) {   // 384 elems, 256 threads: strided
        int b = i / 12, k = i - b * 12;
        const float* P = poses + b * 16;
        if (k < 9) {
            sRd[i] = P[(k / 3) * 4 + (k % 3)];   // R[j][k']
        } else {
            int kk = k - 9;                       // (t.R)[kk], fma-chain rounding
            sRd[i] = fmaf(P[11], P[8 + kk], fmaf(P[7], P[4 + kk], P[3] * P[kk]));
        }
    }
    if (tid < GRIDN) {
        float w = (2.0f * (float)tid) / 127.0f - 1.0f;   // IEEE ufunc order
        sc0[tid] = __fmul_rn(w, S0);
    }
    if (tid == 0) { sax[0] = intr[2] / intr[0]; sax[1] = intr[3] / intr[1]; }
    __syncthreads();

    const int lane = tid & 63;
    const uint32_t wbase = (uint32_t)blockIdx.x * CPB + ((uint32_t)(tid >> 6)) * 512u;
    const int mA = (int)(wbase + 8u * (uint32_t)lane);

    // ---- EARLY epilogue loads, issued right AFTER the barrier: no intervening
    // barrier before use, so ~600cy of decode+classify+phase-2 hides the latency ----
    const float4 dg0lo = *reinterpret_cast<const float4*>(dg + mA);
    const float4 dg0hi = *reinterpret_cast<const float4*>(dg + mA + 4);
    const float4 dg1lo = *reinterpret_cast<const float4*>(dg + NCELLS + mA);
    const float4 dg1hi = *reinterpret_cast<const float4*>(dg + NCELLS + mA + 4);
    const float4 dg2lo = *reinterpret_cast<const float4*>(dg + 2 * NCELLS + mA);
    const float4 dg2hi = *reinterpret_cast<const float4*>(dg + 2 * NCELLS + mA + 4);

    // in-wave morton decode: cell = wbase + 8*lane + s, s in [0,8)
    const int xi = ((lane & 1) << 1) | (((lane >> 3) & 1) << 2);
    const int yi = (((lane >> 1) & 1) << 1) | (((lane >> 4) & 1) << 2);
    const int zi = (((lane >> 2) & 1) << 1) | (((lane >> 5) & 1) << 2);
    const int X0 = compact1by2(wbase);            // multiple of 8; wave box x: X0..X0+7
    const int Y0 = compact1by2(wbase >> 1);       // multiple of 8
    const int Z0 = compact1by2(wbase >> 2);       // multiple of 8
    const float cxv[2] = { sc0[X0 + xi], sc0[X0 + xi + 1] };
    const float cyv[2] = { sc0[Y0 + yi], sc0[Y0 + yi + 1] };
    const float czv[2] = { sc0[Z0 + zi], sc0[Z0 + zi + 1] };
    const float ax = sax[0], ay = sax[1];

    // ---- phase 1: wave box (8x8x8 cells) center/halfwidth; sc0 monotonic ----
    const float gxl = sc0[X0], gxh = sc0[X0 + 7];
    const float gyl = sc0[Y0], gyh = sc0[Y0 + 7];
    const float gzl = sc0[Z0], gzh = sc0[Z0 + 7];
    const float gcx = 0.5f * (gxl + gxh), ghx = 0.5f * (gxh - gxl);
    const float gcy = 0.5f * (gyl + gyh), ghy = 0.5f * (gyh - gyl);
    const float gcz = 0.5f * (gzl + gzh), ghz = 0.5f * (gzh - gzl);

    // lane l classifies camera (l & 31) via 5-plane SAT (rounds 10-14 validated)
    const int cb = lane & 31;
    bool po0, in0, po1, in1, po2, in2;
    {
        const float4* A = reinterpret_cast<const float4*>(&sRd[cb * 12]);
        const float4 qa = A[0], qb = A[1], qc = A[2];
        const float ddx = qc.y, ddy = qc.z, ddz = qc.w;
        const float pcx = fmaf(gcz, qb.z, fmaf(gcy, qa.w, gcx * qa.x));
        const float pcy = fmaf(gcz, qb.w, fmaf(gcy, qb.x, gcx * qa.y));
        const float pcz = fmaf(gcz, qc.x, fmaf(gcy, qb.y, gcx * qa.z));
        // 5 linear forms: F0=z, F1=ax*z-x, F2=ax*z+x, F3=ay*z-y, F4=ay*z+y
        const float F1 = fmaf(ax, pcz, -pcx), F2 = fmaf(ax, pcz, pcx);
        const float F3 = fmaf(ay, pcz, -pcy), F4 = fmaf(ay, pcz, pcy);
        const float r0 = fmaf(ghz, fabsf(qc.x), fmaf(ghy, fabsf(qb.y), ghx * fabsf(qa.z)));
        const float a1x = fmaf(ax, qa.z, -qa.x), a1y = fmaf(ax, qb.y, -qa.w), a1z = fmaf(ax, qc.x, -qb.z);
        const float a2x = fmaf(ax, qa.z,  qa.x), a2y = fmaf(ax, qb.y,  qa.w), a2z = fmaf(ax, qc.x,  qb.z);
        const float a3x = fmaf(ay, qa.z, -qa.y), a3y = fmaf(ay, qb.y, -qb.x), a3z = fmaf(ay, qc.x, -qb.w);
        const float a4x = fmaf(ay, qa.z,  qa.y), a4y = fmaf(ay, qb.y,  qb.x), a4z = fmaf(ay, qc.x,  qb.w);
        const float r1 = fmaf(ghz, fabsf(a1z), fmaf(ghy, fabsf(a1y), ghx * fabsf(a1x)));
        const float r2 = fmaf(ghz, fabsf(a2z), fmaf(ghy, fabsf(a2y), ghx * fabsf(a2x)));
        const float r3 = fmaf(ghz, fabsf(a3z), fmaf(ghy, fabsf(a3y), ghx * fabsf(a3x)));
        const float r4 = fmaf(ghz, fabsf(a4z), fmaf(ghy, fabsf(a4y), ghx * fabsf(a4x)));
        const float e1 = fmaf(ax, ddz, -ddx), e2 = fmaf(ax, ddz, ddx);
        const float e3 = fmaf(ay, ddz, -ddy), e4 = fmaf(ay, ddz, ddy);

        auto classify = [&](float s, float T, bool& poss, bool& allin) {
            const float w0 = fmaf(s, pcz, -ddz);
            const float w1 = fmaf(s, F1, T - e1);
            const float w2 = fmaf(s, F2, T - e2);
            const float w3 = fmaf(s, F3, T - e3);
            const float w4 = fmaf(s, F4, T - e4);
            const float m0h = fmaf(s, r0, w0), m0l = fmaf(-s, r0, w0);
            const float m1h = fmaf(s, r1, w1), m1l = fmaf(-s, r1, w1);
            const float m2h = fmaf(s, r2, w2), m2l = fmaf(-s, r2, w2);
            const float m3h = fmaf(s, r3, w3), m3l = fmaf(-s, r3, w3);
            const float m4h = fmaf(s, r4, w4), m4l = fmaf(-s, r4, w4);
            poss  = !((m0h <= -PAD) | (m1h <= -PAD) | (m2h <= -PAD)
                                    | (m3h <= -PAD) | (m4h <= -PAD));
            allin = (m0l >= PAD) & (m1l >= PAD) & (m2l >= PAD)
                                 & (m3l >= PAD) & (m4l >= PAD);
        };
        classify(1.0f, T0, po0, in0);
        classify(2.0f, T1, po1, in1);
        classify(4.0f, T2, po2, in2);
    }

    const uint32_t allin0 = (uint32_t)__ballot(in0);
    const uint32_t allin1 = (uint32_t)__ballot(in1);
    const uint32_t allin2 = (uint32_t)__ballot(in2);
    const uint32_t poss0  = (uint32_t)__ballot(po0);
    const uint32_t poss1  = (uint32_t)__ballot(po1);
    const uint32_t poss2  = (uint32_t)__ballot(po2);

    const bool sat0 = (allin0 != 0u), sat1 = (allin1 != 0u), sat2 = (allin2 != 0u);
    // per-lane 8-bit visibility masks; cell s = x + 2y + 4z (memory order 8*lane+s)
    uint32_t v0m = sat0 ? 0xffu : 0u;
    uint32_t v1m = sat1 ? 0xffu : 0u;
    uint32_t v2m = sat2 ? 0xffu : 0u;
    bool d0 = sat0, d1 = sat1, d2 = sat2;   // cascade done wave-wide (uniform)

    // ---- phase 2: exact per-cell tests for silhouette cameras only ----
    const uint32_t u0 = sat0 ? 0u : poss0;
    const uint32_t u1 = sat1 ? 0u : poss1;
    const uint32_t u2 = sat2 ? 0u : poss2;
    uint32_t u = u0 | u1 | u2;
    while (u) {
        const int b = __ffs(u) - 1;
        const uint32_t bit = 1u << b;
        u &= u - 1;
        const float4* B = reinterpret_cast<const float4*>(&sRd[b * 12]);
        const float4 qa = B[0], qb = B[1], qc = B[2];
        const bool t0 = ((u0 & bit) != 0u) & !d0;   // wave-uniform -> scalar branches
        const bool t1 = ((u1 & bit) != 0u) & !d1;
        const bool t2 = ((u2 & bit) != 0u) & !d2;

        // 8 cells share chain prefixes; each cell's full chain is the bit-exact
        // validated sequence fmaf(cz, R2k, fmaf(cy, R1k, cx*R0k)).
        float p0[8], p1[8], p2[8];
        #pragma unroll
        for (int x = 0; x < 2; ++x) {
            const float i0 = cxv[x] * qa.x;
            const float i1 = cxv[x] * qa.y;
            const float i2 = cxv[x] * qa.z;
            #pragma unroll
            for (int y = 0; y < 2; ++y) {
                const float j0 = fmaf(cyv[y], qa.w, i0);
                const float j1 = fmaf(cyv[y], qb.x, i1);
                const float j2 = fmaf(cyv[y], qb.y, i2);
                #pragma unroll
                for (int z = 0; z < 2; ++z) {
                    const int s = x + 2 * y + 4 * z;
                    p0[s] = fmaf(czv[z], qb.z, j0);
                    p1[s] = fmaf(czv[z], qb.w, j1);
                    p2[s] = fmaf(czv[z], qc.x, j2);
                }
            }
        }

        if (t0) {   // cascade 0: cam = p - d
            #pragma unroll
            for (int s = 0; s < 8; ++s) {
                const float zz = __fsub_rn(p2[s], qc.w);
                const float xx = __fsub_rn(p0[s], qc.y);
                const float yy = __fsub_rn(p1[s], qc.z);
                const bool c = (zz > 0.0f)
                             & (fabsf(xx) < __fadd_rn(__fmul_rn(ax, zz), T0))
                             & (fabsf(yy) < __fadd_rn(__fmul_rn(ay, zz), T0));
                v0m |= c ? (1u << s) : 0u;
            }
            d0 = __all(v0m == 0xffu);
        }
        if (t1) {   // cascade 1: cam = 2*p - d (exact pow2 scaling)
            #pragma unroll
            for (int s = 0; s < 8; ++s) {
                const float zz = fmaf(2.0f, p2[s], -qc.w);
                const float xx = fmaf(2.0f, p0[s], -qc.y);
                const float yy = fmaf(2.0f, p1[s], -qc.z);
                const bool c = (zz > 0.0f)
                             & (fabsf(xx) < __fadd_rn(__fmul_rn(ax, zz), T1))
                             & (fabsf(yy) < __fadd_rn(__fmul_rn(ay, zz), T1));
                v1m |= c ? (1u << s) : 0u;
            }
            d1 = __all(v1m == 0xffu);
        }
        if (t2) {   // cascade 2: cam = 4*p - d
            #pragma unroll
            for (int s = 0; s < 8; ++s) {
                const float zz = fmaf(4.0f, p2[s], -qc.w);
                const float xx = fmaf(4.0f, p0[s], -qc.y);
                const float yy = fmaf(4.0f, p1[s], -qc.z);
                const bool c = (zz > 0.0f)
                             & (fabsf(xx) < __fadd_rn(__fmul_rn(ax, zz), T2))
                             & (fabsf(yy) < __fadd_rn(__fmul_rn(ay, zz), T2));
                v2m |= c ? (1u << s) : 0u;
            }
            d2 = __all(v2m == 0xffu);
        }

        // dynamic cascade-done stripping: drop cams pending only for finished cascades
        u &= (d0 ? 0u : u0) | (d1 ? 0u : u1) | (d2 ? 0u : u2);
    }

    // ---- epilogue: select from preloaded values, 2x dwordx4 stores per cascade ----
    {
        float4 olo, ohi;
        olo.x = (v0m & 0x01u) ? dg0lo.x : -1.0f; olo.y = (v0m & 0x02u) ? dg0lo.y : -1.0f;
        olo.z = (v0m & 0x04u) ? dg0lo.z : -1.0f; olo.w = (v0m & 0x08u) ? dg0lo.w : -1.0f;
        ohi.x = (v0m & 0x10u) ? dg0hi.x : -1.0f; ohi.y = (v0m & 0x20u) ? dg0hi.y : -1.0f;
        ohi.z = (v0m & 0x40u) ? dg0hi.z : -1.0f; ohi.w = (v0m & 0x80u) ? dg0hi.w : -1.0f;
        *reinterpret_cast<float4*>(out + mA)     = olo;
        *reinterpret_cast<float4*>(out + mA + 4) = ohi;
    }
    {
        float4 olo, ohi;
        olo.x = (v1m & 0x01u) ? dg1lo.x : -1.0f; olo.y = (v1m & 0x02u) ? dg1lo.y : -1.0f;
        olo.z = (v1m & 0x04u) ? dg1lo.z : -1.0f; olo.w = (v1m & 0x08u) ? dg1lo.w : -1.0f;
        ohi.x = (v1m & 0x10u) ? dg1hi.x : -1.0f; ohi.y = (v1m & 0x20u) ? dg1hi.y : -1.0f;
        ohi.z = (v1m & 0x40u) ? dg1hi.z : -1.0f; ohi.w = (v1m & 0x80u) ? dg1hi.w : -1.0f;
        *reinterpret_cast<float4*>(out + NCELLS + mA)     = olo;
        *reinterpret_cast<float4*>(out + NCELLS + mA + 4) = ohi;
    }
    {
        float4 olo, ohi;
        olo.x = (v2m & 0x01u) ? dg2lo.x : -1.0f; olo.y = (v2m & 0x02u) ? dg2lo.y : -1.0f;
        olo.z = (v2m & 0x04u) ? dg2lo.z : -1.0f; olo.w = (v2m & 0x08u) ? dg2lo.w : -1.0f;
        ohi.x = (v2m & 0x10u) ? dg2hi.x : -1.0f; ohi.y = (v2m & 0x20u) ? dg2hi.y : -1.0f;
        ohi.z = (v2m & 0x40u) ? dg2hi.z : -1.0f; ohi.w = (v2m & 0x80u) ? dg2hi.w : -1.0f;
        *reinterpret_cast<float4*>(out + 2 * NCELLS + mA)     = olo;
        *reinterpret_cast<float4*>(out + 2 * NCELLS + mA + 4) = ohi;
    }
}

extern "C" void kernel_launch(void* const* d_in, const int* in_sizes, int n_in,
                              void* d_out, int out_size, void* d_ws, size_t ws_size,
                              hipStream_t stream) {
    const float* dg    = (const float*)d_in[0];   // (3, 128^3) f32
    const float* poses = (const float*)d_in[1];   // (32, 4, 4) f32
    const float* intr  = (const float*)d_in[2];   // (4,) f32
    float* out = (float*)d_out;                   // (3, 128^3) f32

    nerf_mark_kernel<<<NCELLS / CPB, BLOCK, 0, stream>>>(dg, poses, intr, out);
}

// Round 17
// 15.262 us; speedup vs baseline: 1.1064x; 1.1064x over previous
//
#include <hip/hip_runtime.h>
#include <stdint.h>

// NeRF "mark untrained cells": out[cas][m] = visible(cas, morton_decode(m)) ? density[cas][m] : -1
//
// FINAL KERNEL = round 14 exactly (best validated: 15.69us, absmax 0.0).
// Session ledger (16 rounds, all absmax 0.0 after r3):
//   r3  68.8us  baseline exact kernel (per-cell, all 32 cams, np-matched fp semantics)
//   r5  61.5us  shared dot across cascades via exact pow2 scaling (cam = fma(2^c,p,-d))
//   r8  24.0us  per-wave conservative camera culling (interval test + ballot)
//   r10 20.75   5-plane SAT classifier + 2 cells/thread
//   r12 15.74   8 cells/thread (2x2x2/lane, wave = 8x8x8 box, 4096 waves)
//   r14 15.69   + cascade-done stripping + load-skip epilogue (neutral but kept)
// Exhausted: 16 cells/thread (r13: 21.7), early dg loads pre-barrier (r15: 16.7,
// barrier drains vmcnt) and post-barrier (r16: 16.9, unconditional fetch + contention).
// Plateau decomposition: ~3.3us VALU issue + ~5us memory + latency/tail at 4 waves/SIMD.
// This is the practical floor of the culled-exact algorithm, NOT a HW roofline.

constexpr int GRIDN  = 128;
constexpr int NCELLS = GRIDN * GRIDN * GRIDN;   // 2097152
constexpr int NCAMS  = 32;
constexpr int BLOCK  = 256;
constexpr int CPB    = BLOCK * 8;               // 2048 cells per block

__device__ __forceinline__ uint32_t compact1by2(uint32_t x) {
    // inverse of reference _part1by2 (valid for 21-bit morton codes)
    x &= 0x09249249u;
    x = (x ^ (x >> 2))  & 0x030c30c3u;
    x = (x ^ (x >> 4))  & 0x0300f00fu;
    x = (x ^ (x >> 8))  & 0x030000ffu;
    x = (x ^ (x >> 16)) & 0x000003ffu;
    return x;
}

__launch_bounds__(BLOCK)
__global__ void nerf_mark_kernel(const float* __restrict__ dg,
                                 const float* __restrict__ poses,
                                 const float* __restrict__ intr,
                                 float* __restrict__ out) {
    // one 48B record per camera: R0..R8, dx, dy, dz  (16B aligned -> 3x ds_read_b128)
    __shared__ __align__(16) float sRd[NCAMS * 12];
    __shared__ float sc0[GRIDN];      // c0 table: round((2i/127 - 1) * S0)
    __shared__ float sax[2];          // cx/fx, cy/fy

    constexpr float S0  = 1.0f - 1.0f / 128.0f;   // 127/128, exact
    constexpr float T0  = 2.0f / 128.0f, T1 = 4.0f / 128.0f, T2 = 8.0f / 128.0f;
    constexpr float PAD = 1e-3f;                  // >> worst-case fp error (~4e-5)

    const int tid = threadIdx.x;
    for (int i = tid; i < NCAMS * 12; i += BLOCK) {   // 384 elems, 256 threads: strided
        int b = i / 12, k = i - b * 12;
        const float* P = poses + b * 16;
        if (k < 9) {
            sRd[i] = P[(k / 3) * 4 + (k % 3)];   // R[j][k']
        } else {
            int kk = k - 9;                       // (t.R)[kk], fma-chain rounding
            sRd[i] = fmaf(P[11], P[8 + kk], fmaf(P[7], P[4 + kk], P[3] * P[kk]));
        }
    }
    if (tid < GRIDN) {
        float w = (2.0f * (float)tid) / 127.0f - 1.0f;   // IEEE ufunc order
        sc0[tid] = __fmul_rn(w, S0);
    }
    if (tid == 0) { sax[0] = intr[2] / intr[0]; sax[1] = intr[3] / intr[1]; }
    __syncthreads();

    const int lane = tid & 63;
    const uint32_t wbase = (uint32_t)blockIdx.x * CPB + ((uint32_t)(tid >> 6)) * 512u;

    // in-wave morton decode: cell = wbase + 8*lane + s, s in [0,8)
    const int xi = ((lane & 1) << 1) | (((lane >> 3) & 1) << 2);
    const int yi = (((lane >> 1) & 1) << 1) | (((lane >> 4) & 1) << 2);
    const int zi = (((lane >> 2) & 1) << 1) | (((lane >> 5) & 1) << 2);
    const int X0 = compact1by2(wbase);            // multiple of 8; wave box x: X0..X0+7
    const int Y0 = compact1by2(wbase >> 1);       // multiple of 8
    const int Z0 = compact1by2(wbase >> 2);       // multiple of 8
    const float cxv[2] = { sc0[X0 + xi], sc0[X0 + xi + 1] };
    const float cyv[2] = { sc0[Y0 + yi], sc0[Y0 + yi + 1] };
    const float czv[2] = { sc0[Z0 + zi], sc0[Z0 + zi + 1] };
    const float ax = sax[0], ay = sax[1];

    // ---- phase 1: wave box (8x8x8 cells) center/halfwidth; sc0 monotonic ----
    const float gxl = sc0[X0], gxh = sc0[X0 + 7];
    const float gyl = sc0[Y0], gyh = sc0[Y0 + 7];
    const float gzl = sc0[Z0], gzh = sc0[Z0 + 7];
    const float gcx = 0.5f * (gxl + gxh), ghx = 0.5f * (gxh - gxl);
    const float gcy = 0.5f * (gyl + gyh), ghy = 0.5f * (gyh - gyl);
    const float gcz = 0.5f * (gzl + gzh), ghz = 0.5f * (gzh - gzl);

    // lane l classifies camera (l & 31) via 5-plane SAT (rounds 10-14 validated)
    const int cb = lane & 31;
    bool po0, in0, po1, in1, po2, in2;
    {
        const float4* A = reinterpret_cast<const float4*>(&sRd[cb * 12]);
        const float4 qa = A[0], qb = A[1], qc = A[2];
        const float ddx = qc.y, ddy = qc.z, ddz = qc.w;
        const float pcx = fmaf(gcz, qb.z, fmaf(gcy, qa.w, gcx * qa.x));
        const float pcy = fmaf(gcz, qb.w, fmaf(gcy, qb.x, gcx * qa.y));
        const float pcz = fmaf(gcz, qc.x, fmaf(gcy, qb.y, gcx * qa.z));
        // 5 linear forms: F0=z, F1=ax*z-x, F2=ax*z+x, F3=ay*z-y, F4=ay*z+y
        const float F1 = fmaf(ax, pcz, -pcx), F2 = fmaf(ax, pcz, pcx);
        const float F3 = fmaf(ay, pcz, -pcy), F4 = fmaf(ay, pcz, pcy);
        const float r0 = fmaf(ghz, fabsf(qc.x), fmaf(ghy, fabsf(qb.y), ghx * fabsf(qa.z)));
        const float a1x = fmaf(ax, qa.z, -qa.x), a1y = fmaf(ax, qb.y, -qa.w), a1z = fmaf(ax, qc.x, -qb.z);
        const float a2x = fmaf(ax, qa.z,  qa.x), a2y = fmaf(ax, qb.y,  qa.w), a2z = fmaf(ax, qc.x,  qb.z);
        const float a3x = fmaf(ay, qa.z, -qa.y), a3y = fmaf(ay, qb.y, -qb.x), a3z = fmaf(ay, qc.x, -qb.w);
        const float a4x = fmaf(ay, qa.z,  qa.y), a4y = fmaf(ay, qb.y,  qb.x), a4z = fmaf(ay, qc.x,  qb.w);
        const float r1 = fmaf(ghz, fabsf(a1z), fmaf(ghy, fabsf(a1y), ghx * fabsf(a1x)));
        const float r2 = fmaf(ghz, fabsf(a2z), fmaf(ghy, fabsf(a2y), ghx * fabsf(a2x)));
        const float r3 = fmaf(ghz, fabsf(a3z), fmaf(ghy, fabsf(a3y), ghx * fabsf(a3x)));
        const float r4 = fmaf(ghz, fabsf(a4z), fmaf(ghy, fabsf(a4y), ghx * fabsf(a4x)));
        const float e1 = fmaf(ax, ddz, -ddx), e2 = fmaf(ax, ddz, ddx);
        const float e3 = fmaf(ay, ddz, -ddy), e4 = fmaf(ay, ddz, ddy);

        auto classify = [&](float s, float T, bool& poss, bool& allin) {
            const float w0 = fmaf(s, pcz, -ddz);
            const float w1 = fmaf(s, F1, T - e1);
            const float w2 = fmaf(s, F2, T - e2);
            const float w3 = fmaf(s, F3, T - e3);
            const float w4 = fmaf(s, F4, T - e4);
            const float m0h = fmaf(s, r0, w0), m0l = fmaf(-s, r0, w0);
            const float m1h = fmaf(s, r1, w1), m1l = fmaf(-s, r1, w1);
            const float m2h = fmaf(s, r2, w2), m2l = fmaf(-s, r2, w2);
            const float m3h = fmaf(s, r3, w3), m3l = fmaf(-s, r3, w3);
            const float m4h = fmaf(s, r4, w4), m4l = fmaf(-s, r4, w4);
            poss  = !((m0h <= -PAD) | (m1h <= -PAD) | (m2h <= -PAD)
                                    | (m3h <= -PAD) | (m4h <= -PAD));
            allin = (m0l >= PAD) & (m1l >= PAD) & (m2l >= PAD)
                                 & (m3l >= PAD) & (m4l >= PAD);
        };
        classify(1.0f, T0, po0, in0);
        classify(2.0f, T1, po1, in1);
        classify(4.0f, T2, po2, in2);
    }

    const uint32_t allin0 = (uint32_t)__ballot(in0);
    const uint32_t allin1 = (uint32_t)__ballot(in1);
    const uint32_t allin2 = (uint32_t)__ballot(in2);
    const uint32_t poss0  = (uint32_t)__ballot(po0);
    const uint32_t poss1  = (uint32_t)__ballot(po1);
    const uint32_t poss2  = (uint32_t)__ballot(po2);

    const bool sat0 = (allin0 != 0u), sat1 = (allin1 != 0u), sat2 = (allin2 != 0u);
    // per-lane 8-bit visibility masks; cell s = x + 2y + 4z (memory order 8*lane+s)
    uint32_t v0m = sat0 ? 0xffu : 0u;
    uint32_t v1m = sat1 ? 0xffu : 0u;
    uint32_t v2m = sat2 ? 0xffu : 0u;
    bool d0 = sat0, d1 = sat1, d2 = sat2;   // cascade done wave-wide (uniform)

    // ---- phase 2: exact per-cell tests for silhouette cameras only ----
    const uint32_t u0 = sat0 ? 0u : poss0;
    const uint32_t u1 = sat1 ? 0u : poss1;
    const uint32_t u2 = sat2 ? 0u : poss2;
    uint32_t u = u0 | u1 | u2;
    while (u) {
        const int b = __ffs(u) - 1;
        const uint32_t bit = 1u << b;
        u &= u - 1;
        const float4* B = reinterpret_cast<const float4*>(&sRd[b * 12]);
        const float4 qa = B[0], qb = B[1], qc = B[2];
        const bool t0 = ((u0 & bit) != 0u) & !d0;   // wave-uniform -> scalar branches
        const bool t1 = ((u1 & bit) != 0u) & !d1;
        const bool t2 = ((u2 & bit) != 0u) & !d2;

        // 8 cells share chain prefixes; each cell's full chain is the bit-exact
        // validated sequence fmaf(cz, R2k, fmaf(cy, R1k, cx*R0k)).
        float p0[8], p1[8], p2[8];
        #pragma unroll
        for (int x = 0; x < 2; ++x) {
            const float i0 = cxv[x] * qa.x;
            const float i1 = cxv[x] * qa.y;
            const float i2 = cxv[x] * qa.z;
            #pragma unroll
            for (int y = 0; y < 2; ++y) {
                const float j0 = fmaf(cyv[y], qa.w, i0);
                const float j1 = fmaf(cyv[y], qb.x, i1);
                const float j2 = fmaf(cyv[y], qb.y, i2);
                #pragma unroll
                for (int z = 0; z < 2; ++z) {
                    const int s = x + 2 * y + 4 * z;
                    p0[s] = fmaf(czv[z], qb.z, j0);
                    p1[s] = fmaf(czv[z], qb.w, j1);
                    p2[s] = fmaf(czv[z], qc.x, j2);
                }
            }
        }

        if (t0) {   // cascade 0: cam = p - d
            #pragma unroll
            for (int s = 0; s < 8; ++s) {
                const float zz = __fsub_rn(p2[s], qc.w);
                const float xx = __fsub_rn(p0[s], qc.y);
                const float yy = __fsub_rn(p1[s], qc.z);
                const bool c = (zz > 0.0f)
                             & (fabsf(xx) < __fadd_rn(__fmul_rn(ax, zz), T0))
                             & (fabsf(yy) < __fadd_rn(__fmul_rn(ay, zz), T0));
                v0m |= c ? (1u << s) : 0u;
            }
            d0 = __all(v0m == 0xffu);
        }
        if (t1) {   // cascade 1: cam = 2*p - d (exact pow2 scaling)
            #pragma unroll
            for (int s = 0; s < 8; ++s) {
                const float zz = fmaf(2.0f, p2[s], -qc.w);
                const float xx = fmaf(2.0f, p0[s], -qc.y);
                const float yy = fmaf(2.0f, p1[s], -qc.z);
                const bool c = (zz > 0.0f)
                             & (fabsf(xx) < __fadd_rn(__fmul_rn(ax, zz), T1))
                             & (fabsf(yy) < __fadd_rn(__fmul_rn(ay, zz), T1));
                v1m |= c ? (1u << s) : 0u;
            }
            d1 = __all(v1m == 0xffu);
        }
        if (t2) {   // cascade 2: cam = 4*p - d
            #pragma unroll
            for (int s = 0; s < 8; ++s) {
                const float zz = fmaf(4.0f, p2[s], -qc.w);
                const float xx = fmaf(4.0f, p0[s], -qc.y);
                const float yy = fmaf(4.0f, p1[s], -qc.z);
                const bool c = (zz > 0.0f)
                             & (fabsf(xx) < __fadd_rn(__fmul_rn(ax, zz), T2))
                             & (fabsf(yy) < __fadd_rn(__fmul_rn(ay, zz), T2));
                v2m |= c ? (1u << s) : 0u;
            }
            d2 = __all(v2m == 0xffu);
        }

        // dynamic cascade-done stripping: drop cams pending only for finished cascades
        u &= (d0 ? 0u : u0) | (d1 ? 0u : u1) | (d2 ? 0u : u2);
    }

    // ---- epilogue: 2x float4 per cascade; skip dg loads if cascade all-invisible ----
    const int mA = (int)(wbase + 8u * (uint32_t)lane);
    #pragma unroll
    for (int cas = 0; cas < 3; ++cas) {
        const uint32_t vm = (cas == 0) ? v0m : (cas == 1) ? v1m : v2m;
        const float* src = dg + cas * NCELLS + mA;
        float* dst = out + cas * NCELLS + mA;
        if (__any(vm != 0u)) {
            const float4 dlo = *reinterpret_cast<const float4*>(src);
            const float4 dhi = *reinterpret_cast<const float4*>(src + 4);
            float4 olo, ohi;
            olo.x = (vm & 0x01u) ? dlo.x : -1.0f; olo.y = (vm & 0x02u) ? dlo.y : -1.0f;
            olo.z = (vm & 0x04u) ? dlo.z : -1.0f; olo.w = (vm & 0x08u) ? dlo.w : -1.0f;
            ohi.x = (vm & 0x10u) ? dhi.x : -1.0f; ohi.y = (vm & 0x20u) ? dhi.y : -1.0f;
            ohi.z = (vm & 0x40u) ? dhi.z : -1.0f; ohi.w = (vm & 0x80u) ? dhi.w : -1.0f;
            *reinterpret_cast<float4*>(dst)     = olo;
            *reinterpret_cast<float4*>(dst + 4) = ohi;
        } else {
            const float4 neg = make_float4(-1.0f, -1.0f, -1.0f, -1.0f);
            *reinterpret_cast<float4*>(dst)     = neg;
            *reinterpret_cast<float4*>(dst + 4) = neg;
        }
    }
}

extern "C" void kernel_launch(void* const* d_in, const int* in_sizes, int n_in,
                              void* d_out, int out_size, void* d_ws, size_t ws_size,
                              hipStream_t stream) {
    const float* dg    = (const float*)d_in[0];   // (3, 128^3) f32
    const float* poses = (const float*)d_in[1];   // (32, 4, 4) f32
    const float* intr  = (const float*)d_in[2];   // (4,) f32
    float* out = (float*)d_out;                   // (3, 128^3) f32

    nerf_mark_kernel<<<NCELLS / CPB, BLOCK, 0, stream>>>(dg, poses, intr, out);
}